// Round 5
// baseline (334.361 us; speedup 1.0000x reference)
//
#include <hip/hip_runtime.h>
#include <math.h>

#define NUM_KV_HEADS 8
#define HEAD_DIM 128
#define HD (NUM_KV_HEADS * HEAD_DIM)    // 1024 floats per token row
#define BLOCK_SZ 16
#define MODEL_CTX 4096
#define TC 64                            // tokens per wave
#define NEG_BIG (-1e30f)

// Kernel 0: rope cos/sin table, indexed by DELTA = pos_q - pos_k.
// float4 at (d*128 + 8*f2) = {cos(f0),sin(f0),cos(f1),sin(f1)} ... layout:
// tab[d*128 + 2f] = cos(d*invf_f), tab[d*128 + 2f + 1] = sin(d*invf_f), f=0..63.
__global__ void rope_table(float* __restrict__ tab, int ntab) {
    const int idx = blockIdx.x * 256 + threadIdx.x;   // d*64 + f
    if (idx >= ntab * 64) return;
    const int d = idx >> 6;
    const int f = idx & 63;
    const float inv = expf(-9.210340371976184f * (float)f * (1.0f / 64.0f));
    float s, c;
    sincosf((float)d * inv, &s, &c);
    tab[2 * idx]     = c;
    tab[2 * idx + 1] = s;
}

// Kernel 1: wave = (b, h, 64-token chunk); LANE = TOKEN. Each lane computes its
// token's full 128-dim score locally (no shuffles, no barriers) using the
// relative-RoPE identity: score = sum_f cos(D*invf)(q1k1+q2k2) + sin(D*invf)(q1k2-q2k1),
// D = (MODEL_CTX-1) - t. Then V pass with lane = dim-pair (coalesced), p and
// row pointers broadcast from wave-private LDS.
__global__ __launch_bounds__(256, 4)
void attn_partial(const float* __restrict__ q,
                  const float* __restrict__ knew,
                  const float* __restrict__ vnew,
                  const float* __restrict__ kcache,
                  const float* __restrict__ vcache,
                  const int* __restrict__ btab,
                  const int* __restrict__ seqlen_p,
                  const float* __restrict__ tab,
                  int nbps,
                  float* __restrict__ o_part,    // [B*H][n_chunks][128]
                  float* __restrict__ m_part,
                  float* __restrict__ l_part,
                  int n_chunks)
{
    const int tid   = threadIdx.x;
    const int wave  = tid >> 6;
    const int lane  = tid & 63;
    const int chunk = blockIdx.x * 4 + wave;
    const int bh    = blockIdx.y;
    const int b     = bh >> 3;

    __shared__ float qsm[4][HEAD_DIM];
    __shared__ float psm[4][TC];
    __shared__ unsigned long long rowp[4][TC];

    const int seq_len = *seqlen_p;
    const int rem = (seq_len - 1) & (BLOCK_SZ - 1);
    const int T   = (nbps - 1) * BLOCK_SZ + rem + 1;

    // stage this wave's raw q head into LDS (one float4 per lane<32)
    const float* qb = q + (size_t)bh * HEAD_DIM;    // b*HD + h*128 == bh*128
    if (lane < HEAD_DIM / 4)
        ((float4*)qsm[wave])[lane] = ((const float4*)qb)[lane];

    // per-lane token setup
    const int t  = chunk * TC + lane;
    const bool nl = (t >= T - 1);          // new token (or OOB; masked below)
    const float* krow;
    const float* vrow;
    int delta;
    if (nl) {
        krow = knew + (size_t)bh * HEAD_DIM;
        vrow = vnew + (size_t)bh * HEAD_DIM;
        delta = 0;
    } else {
        const int blkid = btab[b * nbps + (t >> 4)];
        const size_t row = (size_t)blkid * BLOCK_SZ + (t & 15);
        krow = kcache + row * HD + (bh & 7) * HEAD_DIM;
        vrow = vcache + row * HD + (bh & 7) * HEAD_DIM;
        delta = (MODEL_CTX - 1) - t;
    }
    rowp[wave][lane] = (unsigned long long)vrow;
    const float* csrow = tab + (size_t)delta * 128;

    // ---- K pass: fully lane-local dot ----
    float s0 = 0.f, s1 = 0.f, s2 = 0.f, s3 = 0.f;
    #pragma unroll 4
    for (int i = 0; i < 16; i++) {
        const float4 k1 = *(const float4*)(krow + 4 * i);
        const float4 k2 = *(const float4*)(krow + 64 + 4 * i);
        const float4 ca = *(const float4*)(csrow + 8 * i);
        const float4 cb = *(const float4*)(csrow + 8 * i + 4);
        const float4 q1 = *(const float4*)(&qsm[wave][4 * i]);
        const float4 q2 = *(const float4*)(&qsm[wave][64 + 4 * i]);
        s0 += ca.x * (q1.x * k1.x + q2.x * k2.x) + ca.y * (q1.x * k2.x - q2.x * k1.x);
        s1 += ca.z * (q1.y * k1.y + q2.y * k2.y) + ca.w * (q1.y * k2.y - q2.y * k1.y);
        s2 += cb.x * (q1.z * k1.z + q2.z * k2.z) + cb.y * (q1.z * k2.z - q2.z * k1.z);
        s3 += cb.z * (q1.w * k1.w + q2.w * k2.w) + cb.w * (q1.w * k2.w - q2.w * k1.w);
    }
    float s = (s0 + s1) + (s2 + s3);
    s = (t < T) ? s * 0.08838834764831845f : NEG_BIG;

    // wave softmax (once per 64 tokens, not per token)
    float m = s;
    #pragma unroll
    for (int off = 1; off < 64; off <<= 1) m = fmaxf(m, __shfl_xor(m, off, 64));
    const float p = __expf(s - m);
    float l = p;
    #pragma unroll
    for (int off = 1; off < 64; off <<= 1) l += __shfl_xor(l, off, 64);
    psm[wave][lane] = p;

    // ---- V pass: lane = dim pair (2*lane, 2*lane+1), coalesced rows ----
    float a0 = 0.f, a1 = 0.f;
    #pragma unroll 8
    for (int j = 0; j < TC; j++) {
        const float* vp = (const float*)rowp[wave][j];   // LDS broadcast
        const float pw  = psm[wave][j];                  // LDS broadcast
        const float2 v  = *(const float2*)(vp + 2 * lane);
        a0 += pw * v.x;
        a1 += pw * v.y;
    }

    float* op = o_part + ((size_t)bh * n_chunks + chunk) * HEAD_DIM;
    ((float2*)op)[lane] = make_float2(a0, a1);
    if (lane == 0) {
        m_part[bh * n_chunks + chunk] = m;
        l_part[bh * n_chunks + chunk] = l;
    }
}

// Kernel 2: combine split-K partials.
__global__ void attn_combine(const float* __restrict__ o_part,
                             const float* __restrict__ m_part,
                             const float* __restrict__ l_part,
                             float* __restrict__ out,
                             int n_chunks)
{
    const int bh = blockIdx.x;
    const int d  = threadIdx.x;

    float M = -INFINITY;
    for (int c = 0; c < n_chunks; c++) M = fmaxf(M, m_part[bh * n_chunks + c]);
    float L = 0.f, num = 0.f;
    for (int c = 0; c < n_chunks; c++) {
        const float w = __expf(m_part[bh * n_chunks + c] - M);
        L   += l_part[bh * n_chunks + c] * w;
        num += w * o_part[((size_t)bh * n_chunks + c) * HEAD_DIM + d];
    }
    out[(size_t)bh * HEAD_DIM + d] = num / L;
}

extern "C" void kernel_launch(void* const* d_in, const int* in_sizes, int n_in,
                              void* d_out, int out_size, void* d_ws, size_t ws_size,
                              hipStream_t stream) {
    const float* q  = (const float*)d_in[0];
    const float* k  = (const float*)d_in[1];
    const float* v  = (const float*)d_in[2];
    const float* kc = (const float*)d_in[3];
    const float* vc = (const float*)d_in[4];
    const int* bt   = (const int*)d_in[5];
    const int* slp  = (const int*)d_in[7];

    const int B    = in_sizes[0] / HD;
    const int nbps = in_sizes[5] / B;                     // 256
    const int n_chunks = (nbps * BLOCK_SZ) / TC;          // 64
    const int BH = B * NUM_KV_HEADS;

    int ntab = nbps * BLOCK_SZ;
    if (ntab < MODEL_CTX) ntab = MODEL_CTX;

    float* tab    = (float*)d_ws;                          // ntab*128 floats
    float* o_part = tab + (size_t)ntab * 128;
    float* m_part = o_part + (size_t)BH * n_chunks * HEAD_DIM;
    float* l_part = m_part + (size_t)BH * n_chunks;

    rope_table<<<(ntab * 64 + 255) / 256, 256, 0, stream>>>(tab, ntab);

    dim3 g1(n_chunks / 4, BH);
    attn_partial<<<g1, 256, 0, stream>>>(q, k, v, kc, vc, bt, slp, tab, nbps,
                                         o_part, m_part, l_part, n_chunks);
    attn_combine<<<dim3(BH), HEAD_DIM, 0, stream>>>(o_part, m_part, l_part,
                                                    (float*)d_out, n_chunks);
}